// Round 13
// baseline (49.228 us; speedup 1.0000x reference)
//
#include <hip/hip_runtime.h>
#include <stdint.h>

// QuantDenseModelLarge on gfx950 — MFMA formulation.
// Round 13 = round 12 (41.0 µs) + sequential-burst x prefetch.
// Theory: 41 µs @ 134 MB = 3.4 TB/s vs 7 TB/s sequential on the same machine.
// Compute-phase x reads are 64B-segment gathers (16 rows x 64B per instr) ->
// HBM request-inefficiency. Fix: per-wave dummy global_load_lds prefetch, one
// DMA = one FULL 1KB row (64 lanes x 16B contiguous), 16 rows = 16KB sequential
// stream per wave, drained by the existing staging barrier. Dest = the wave's
// bounce tile (garbage, overwritten by epilog later). Compute path unchanged ->
// bit-identical output; post-barrier x reads hit L1/L2/L3.
//
// Exact identities:
//   quant weights = qw * sw, qw int in [-7,7]  -> exact in bf16
//   QuantReLU out = qa * s,  qa int in [0,255] -> exact in bf16
//   layers 2/3/out: D = sum(qa*qw) exact in f32; y = D*(s*sw)
//   layer 1: x == hi + lo1 + lo2 EXACTLY (3 bf16 truncation limbs cover 24 bits)
//   rint(max(y,0)) == med3(rint(y), 0, 255) for the clamp (rint monotone)
//
// MFMA layout (hardware-verified via learn_hip m89/m92 ref-checked GEMMs):
//   A (16x32): lane l holds A[m = l&15][k = 8*(l>>4) + j], j=0..7
//   B (32x16): lane l holds B[k = 8*(l>>4) + j][n = l&15]
//   C/D      : lane l, reg r holds D[row = 4*(l>>4) + r][col = l&15]

typedef __attribute__((ext_vector_type(4))) float  f32x4;
typedef __attribute__((ext_vector_type(8))) short  bf16x8;
typedef __attribute__((ext_vector_type(4))) unsigned int u32x4;

namespace {
constexpr int B_  = 131072;
constexpr int IN_ = 256;
constexpr int H_  = 58;
constexpr int C_  = 12;

// ws byte offsets (also the LDS image offsets after staging)
constexpr int W1F = 0;        // [ht4][kt8][lane64][j8] bf16 = 32768 B
constexpr int W2F = 32768;    // [ht4][kt2][lane64][j8] bf16 =  8192 B
constexpr int W3F = 40960;    //                                8192 B
constexpr int WOF = 49152;    // [kt2][lane64][j8]      bf16 =  2048 B
constexpr int PAR = 51200;    // 3*64 {A',b'} f32 | bo[16] | {unused x3, So}
constexpr int WS_STAGE = 52816;  // PAR + 404*4, multiple of 16
constexpr int PITCH = 144;    // bounce-tile row pitch (bytes): 128 data + 16 pad
}

__device__ __forceinline__ uint32_t fu(float f) { return __float_as_uint(f); }
__device__ __forceinline__ float    uf(uint32_t u) { return __uint_as_float(u); }
__device__ __forceinline__ float    truncbf(float v) { return uf(fu(v) & 0xffff0000u); }
// pack bf16(a) into low16, bf16(b) into high16 — single v_perm_b32.
__device__ __forceinline__ uint32_t packbf(float a, float b) {
  return __builtin_amdgcn_perm(fu(b), fu(a), 0x07060302u);
}

__device__ __forceinline__ f32x4 MFMA(u32x4 a, bf16x8 b, f32x4 c) {
  union { u32x4 u; bf16x8 s; } ua; ua.u = a;
  return __builtin_amdgcn_mfma_f32_16x16x32_bf16(ua.s, b, c, 0, 0, 0);
}

// ---------------- prep: quantize + fragment-major arrange + param tables ----------------
__global__ void prep_kernel(
    const float* __restrict__ W1, const float* __restrict__ W2,
    const float* __restrict__ W3, const float* __restrict__ Wo,
    const float* __restrict__ g1, const float* __restrict__ b1, const float* __restrict__ s1,
    const float* __restrict__ g2, const float* __restrict__ b2, const float* __restrict__ s2,
    const float* __restrict__ g3, const float* __restrict__ b3, const float* __restrict__ s3,
    const float* __restrict__ bo,
    uint8_t* __restrict__ wsb)
{
  __shared__ float red[1024];
  const int t = threadIdx.x;
  const int blk = blockIdx.x;
  const float* W; int n;
  switch (blk) {
    case 0: W = W1; n = H_ * IN_; break;
    case 1: W = W2; n = H_ * H_;  break;
    case 2: W = W3; n = H_ * H_;  break;
    default: W = Wo; n = C_ * H_; break;
  }
  float m = 0.f;
  for (int i = t; i < n; i += 1024) m = fmaxf(m, fabsf(W[i]));
  red[t] = m;
  __syncthreads();
  for (int s = 512; s > 0; s >>= 1) { if (t < s) red[t] = fmaxf(red[t], red[t + s]); __syncthreads(); }
  const float sw = red[0] / 7.0f;   // per-tensor symmetric, qmax = 7

  float* pp = (float*)(wsb + PAR);

  if (blk == 0) {
    unsigned short* fr = (unsigned short*)(wsb + W1F);
    for (int i = t; i < 16384; i += 1024) {
      const int j = i & 7, ln = (i >> 3) & 63, kt = (i >> 9) & 7, ht = (i >> 12) & 3;
      const int h = (ht << 4) | (ln & 15);
      const int k = (kt << 5) | (((ln >> 4) & 3) << 3) | j;
      float q = 0.f;
      if (h < H_) q = fminf(fmaxf(rintf(W1[h * IN_ + k] / sw), -7.f), 7.f);
      fr[i] = (unsigned short)(fu(q) >> 16);   // small ints exact in bf16
    }
    const float inv = 1.0f / s1[0];
    if (t < 64) {
      pp[2 * t]     = (t < H_) ? sw * g1[t] * inv : 0.f;   // A' = A/s1
      pp[2 * t + 1] = (t < H_) ? b1[t] * inv : 0.f;        // b' = b/s1
    }
  } else if (blk == 1) {
    unsigned short* fr = (unsigned short*)(wsb + W2F);
    for (int i = t; i < 4096; i += 1024) {
      const int j = i & 7, ln = (i >> 3) & 63, kt = (i >> 9) & 1, ht = (i >> 10) & 3;
      const int h = (ht << 4) | (ln & 15);
      const int k = (kt << 5) | (((ln >> 4) & 3) << 3) | j;
      float q = 0.f;
      if (h < H_ && k < H_) q = fminf(fmaxf(rintf(W2[h * H_ + k] / sw), -7.f), 7.f);
      fr[i] = (unsigned short)(fu(q) >> 16);
    }
    const float inv = 1.0f / s2[0];
    if (t < 64) {
      pp[128 + 2 * t]     = (t < H_) ? s1[0] * sw * g2[t] * inv : 0.f;
      pp[128 + 2 * t + 1] = (t < H_) ? b2[t] * inv : 0.f;
    }
  } else if (blk == 2) {
    unsigned short* fr = (unsigned short*)(wsb + W3F);
    for (int i = t; i < 4096; i += 1024) {
      const int j = i & 7, ln = (i >> 3) & 63, kt = (i >> 9) & 1, ht = (i >> 10) & 3;
      const int h = (ht << 4) | (ln & 15);
      const int k = (kt << 5) | (((ln >> 4) & 3) << 3) | j;
      float q = 0.f;
      if (h < H_ && k < H_) q = fminf(fmaxf(rintf(W3[h * H_ + k] / sw), -7.f), 7.f);
      fr[i] = (unsigned short)(fu(q) >> 16);
    }
    const float inv = 1.0f / s3[0];
    if (t < 64) {
      pp[256 + 2 * t]     = (t < H_) ? s2[0] * sw * g3[t] * inv : 0.f;
      pp[256 + 2 * t + 1] = (t < H_) ? b3[t] * inv : 0.f;
    }
  } else {
    unsigned short* fr = (unsigned short*)(wsb + WOF);
    for (int i = t; i < 1024; i += 1024) {
      const int j = i & 7, ln = (i >> 3) & 63, kt = (i >> 9) & 1;
      const int h = ln & 15;
      const int k = (kt << 5) | (((ln >> 4) & 3) << 3) | j;
      float q = 0.f;
      if (h < C_ && k < H_) q = fminf(fmaxf(rintf(Wo[h * H_ + k] / sw), -7.f), 7.f);
      fr[i] = (unsigned short)(fu(q) >> 16);
    }
    if (t < 16) pp[384 + t] = (t < C_) ? bo[t] : 0.f;
    if (t == 0) pp[403] = s3[0] * sw;   // So
  }
}

// ---------------- epilogue: BN+QuantReLU (prescaled) -> bf16 ints -> LDS bounce -> B-frags ----------------
__device__ __forceinline__ void epilog(
    const f32x4 (&acc)[4], const float* pars, int L,
    uint8_t* bw, int g, int c, bf16x8 (&bfr)[2])
{
  const float* pb = pars + L * 128 + 8 * g;   // {A'(h),b'(h)} pairs, h = 16ht+4g+r
#pragma unroll
  for (int ht = 0; ht < 4; ++ht) {
    float q[4];
#pragma unroll
    for (int r = 0; r < 4; ++r) {
      q[r] = __builtin_amdgcn_fmed3f(
          rintf(fmaf(acc[ht][r], pb[32 * ht + 2 * r], pb[32 * ht + 2 * r + 1])),
          0.f, 255.f);
    }
    uint8_t* bp = bw + c * PITCH + 32 * ht + 8 * g;   // row c, bytes 2h..2h+7
    *(uint32_t*)(bp)     = packbf(q[0], q[1]);
    *(uint32_t*)(bp + 4) = packbf(q[2], q[3]);
  }
  // same-wave cross-lane exchange: DS ops from one wave are processed in order
#pragma unroll
  for (int kt = 0; kt < 2; ++kt) {
    const uint8_t* rp = bw + c * PITCH + 64 * kt + 16 * g;  // k = 32kt+8g+j
    union { u32x4 u; bf16x8 s; } uv;
    uv.u = *(const u32x4*)rp;
    bfr[kt] = uv.s;
  }
}

__global__ __launch_bounds__(512, 4) void fused_mfma_kernel(
    const float* __restrict__ x, const uint8_t* __restrict__ wsb,
    float* __restrict__ out)
{
  // Entire ws image (weight fragments + params) staged once per block.
  __shared__ __align__(16) uint8_t wlds[WS_STAGE];
  __shared__ __align__(16) uint8_t bnc[8][16 * PITCH];  // per-wave bounce tiles

  const int t = threadIdx.x;
  const int w = t >> 6, l = t & 63, g = (l >> 4) & 3, c = l & 15;
  const size_t rowbase = (size_t)blockIdx.x * 128;

  // Stage ws -> LDS: 7 chunks of 8KB (512 lanes x 16B), linear both sides.
#pragma unroll
  for (int i = 0; i < 7; ++i) {
    const int off = i * 8192 + t * 16;
    if (off < WS_STAGE) {
      __builtin_amdgcn_global_load_lds(
          (const __attribute__((address_space(1))) void*)(wsb + off),
          (__attribute__((address_space(3))) void*)(wlds + off), 16, 0, 0);
    }
  }

  // this lane's batch row (B-fragment n = l&15); k-slice owned: 8g..8g+7 (+32s)
  const float* __restrict__ xrow = x + (rowbase + 16 * w + c) * IN_;

  // ---- Sequential-burst x prefetch (L1/L2 warm-up) ----
  // One DMA = one FULL row: 64 lanes x 16B = 1KB contiguous. 16 rows per wave
  // = 16KB sequential stream. Dest = this wave's bounce tile (garbage; epilog
  // rewrites it after the barrier). Drained by the staging barrier below.
  {
    const float* wxbase = x + (rowbase + 16 * w) * IN_;
#pragma unroll
    for (int r = 0; r < 16; ++r) {
      __builtin_amdgcn_global_load_lds(
          (const __attribute__((address_space(1))) void*)(wxbase + r * IN_ + 4 * l),
          (__attribute__((address_space(3))) void*)(&bnc[w][0]), 16, 0, 0);
    }
  }

  // Hoist k-tiles 0/1 x loads above the barrier: the barrier's vmcnt(0) drain
  // completes them alongside the staging DMAs -> no post-barrier stall.
  f32x4 xpre[4];
  xpre[0] = *(const f32x4*)(xrow + 8 * g);
  xpre[1] = *(const f32x4*)(xrow + 8 * g + 4);
  xpre[2] = *(const f32x4*)(xrow + 32 + 8 * g);
  xpre[3] = *(const f32x4*)(xrow + 32 + 8 * g + 4);

  __syncthreads();   // drains vmcnt -> staged image + prefetch + xpre ready

  const float* pars = (const float*)(wlds + PAR);
  const float So = pars[403];

  f32x4 acc[4];
#pragma unroll
  for (int ht = 0; ht < 4; ++ht) acc[ht] = f32x4{0.f, 0.f, 0.f, 0.f};

  // ---- Layer 1: 8 k-tiles of 32, 3 exact bf16 limbs; A-frags via ds_read_b128 ----
#pragma unroll
  for (int s = 0; s < 8; ++s) {
    u32x4 wf[4];
#pragma unroll
    for (int ht = 0; ht < 4; ++ht)
      wf[ht] = *(const u32x4*)(wlds + W1F + (size_t)(((ht * 8 + s) * 64) + l) * 16);

    const f32x4 e0 = (s == 0) ? xpre[0] : (s == 1) ? xpre[2]
                     : *(const f32x4*)(xrow + 32 * s + 8 * g);
    const f32x4 e1 = (s == 0) ? xpre[1] : (s == 1) ? xpre[3]
                     : *(const f32x4*)(xrow + 32 * s + 8 * g + 4);
    const float el[8] = {e0.x, e0.y, e0.z, e0.w, e1.x, e1.y, e1.z, e1.w};

    float d[8], e2[8];
#pragma unroll
    for (int q = 0; q < 8; ++q) d[q] = el[q] - truncbf(el[q]);   // exact
#pragma unroll
    for (int q = 0; q < 8; ++q) e2[q] = d[q] - truncbf(d[q]);    // exact

    union { uint32_t u[4]; bf16x8 v; } bh, bl1, bl2;
#pragma unroll
    for (int q = 0; q < 4; ++q) {
      bh.u[q]  = packbf(el[2 * q], el[2 * q + 1]);
      bl1.u[q] = packbf(d[2 * q],  d[2 * q + 1]);
      bl2.u[q] = packbf(e2[2 * q], e2[2 * q + 1]);
    }
#pragma unroll
    for (int ht = 0; ht < 4; ++ht) acc[ht] = MFMA(wf[ht], bh.v,  acc[ht]);
#pragma unroll
    for (int ht = 0; ht < 4; ++ht) acc[ht] = MFMA(wf[ht], bl1.v, acc[ht]);
#pragma unroll
    for (int ht = 0; ht < 4; ++ht) acc[ht] = MFMA(wf[ht], bl2.v, acc[ht]);
  }

  uint8_t* bw = &bnc[w][0];
  bf16x8 bfr[2];

  // ---- Layer 2 ----
  epilog(acc, pars, 0, bw, g, c, bfr);
  f32x4 a2[4];
#pragma unroll
  for (int ht = 0; ht < 4; ++ht) a2[ht] = f32x4{0.f, 0.f, 0.f, 0.f};
#pragma unroll
  for (int kt = 0; kt < 2; ++kt) {
#pragma unroll
    for (int ht = 0; ht < 4; ++ht) {
      const u32x4 wf = *(const u32x4*)(wlds + W2F + (size_t)(((ht * 2 + kt) * 64) + l) * 16);
      a2[ht] = MFMA(wf, bfr[kt], a2[ht]);
    }
  }

  // ---- Layer 3 ----
  epilog(a2, pars, 1, bw, g, c, bfr);
  f32x4 a3[4];
#pragma unroll
  for (int ht = 0; ht < 4; ++ht) a3[ht] = f32x4{0.f, 0.f, 0.f, 0.f};
#pragma unroll
  for (int kt = 0; kt < 2; ++kt) {
#pragma unroll
    for (int ht = 0; ht < 4; ++ht) {
      const u32x4 wf = *(const u32x4*)(wlds + W3F + (size_t)(((ht * 2 + kt) * 64) + l) * 16);
      a3[ht] = MFMA(wf, bfr[kt], a3[ht]);
    }
  }

  // ---- Output layer ----
  epilog(a3, pars, 2, bw, g, c, bfr);
  f32x4 ao = f32x4{0.f, 0.f, 0.f, 0.f};
#pragma unroll
  for (int kt = 0; kt < 2; ++kt) {
    const u32x4 wf = *(const u32x4*)(wlds + WOF + (size_t)((kt * 64) + l) * 16);
    ao = MFMA(wf, bfr[kt], ao);
  }

  const float bo0 = pars[384 + 4 * g + 0];
  const float bo1 = pars[384 + 4 * g + 1];
  const float bo2 = pars[384 + 4 * g + 2];
  const float bo3 = pars[384 + 4 * g + 3];
  f32x4 o;
  o.x = fmaf(ao.x, So, bo0);
  o.y = fmaf(ao.y, So, bo1);
  o.z = fmaf(ao.z, So, bo2);
  o.w = fmaf(ao.w, So, bo3);
  if (g < 3)  // out channels 4g..4g+3; only 0..11 exist
    *(f32x4*)(out + (rowbase + 16 * w + c) * C_ + 4 * g) = o;
}

extern "C" void kernel_launch(void* const* d_in, const int* in_sizes, int n_in,
                              void* d_out, int out_size, void* d_ws, size_t ws_size,
                              hipStream_t stream) {
  // 0:x 1:W1 2:g1 3:b1 4:s1 5:W2 6:g2 7:b2 8:s2 9:W3 10:g3 11:b3 12:s3 13:Wo 14:bo
  const float* x  = (const float*)d_in[0];
  const float* W1 = (const float*)d_in[1];
  const float* g1 = (const float*)d_in[2];
  const float* b1 = (const float*)d_in[3];
  const float* s1 = (const float*)d_in[4];
  const float* W2 = (const float*)d_in[5];
  const float* g2 = (const float*)d_in[6];
  const float* b2 = (const float*)d_in[7];
  const float* s2 = (const float*)d_in[8];
  const float* W3 = (const float*)d_in[9];
  const float* g3 = (const float*)d_in[10];
  const float* b3 = (const float*)d_in[11];
  const float* s3 = (const float*)d_in[12];
  const float* Wo = (const float*)d_in[13];
  const float* bo = (const float*)d_in[14];

  uint8_t* ws = (uint8_t*)d_ws;
  float* out = (float*)d_out;

  prep_kernel<<<4, 1024, 0, stream>>>(W1, W2, W3, Wo, g1, b1, s1, g2, b2, s2,
                                      g3, b3, s3, bo, ws);
  fused_mfma_kernel<<<B_ / 128, 512, 0, stream>>>(x, ws, out);
}

// Round 14
// 44.851 us; speedup vs baseline: 1.0976x; 1.0976x over previous
//
#include <hip/hip_runtime.h>
#include <stdint.h>

// QuantDenseModelLarge on gfx950 — MFMA formulation.
// Round 14 = r12 weight-LDS/epilog + r9 (verified-correct) x DMA double-buffer.
// Theory: r13 showed x streams at 16.4 TB/s (L3-resident) via sequential DMA,
// while the compute phase extracts only 3.4 TB/s -> request-concurrency bound
// (~2-4KB/wave in flight vs ~32KB/CU needed at ~500cy L3 latency).
// global_load_lds double-buffer keeps 4KB/wave in flight with zero VGPR cost:
// 8 waves x 4KB = 32KB/CU. 512-thr blocks, 1 block/CU (LDS 136.8KB).
//
// Exact identities:
//   quant weights = qw * sw, qw int in [-7,7]  -> exact in bf16
//   QuantReLU out = qa * s,  qa int in [0,255] -> exact in bf16
//   layers 2/3/out: D = sum(qa*qw) exact in f32; y = D*(s*sw)
//   layer 1: x == hi + lo1 + lo2 EXACTLY (3 bf16 truncation limbs cover 24 bits)
//   rint(max(y,0)) == med3(rint(y), 0, 255) for the clamp (rint monotone)
//
// MFMA layout (hardware-verified via learn_hip m89/m92 ref-checked GEMMs):
//   A (16x32): lane l holds A[m = l&15][k = 8*(l>>4) + j], j=0..7
//   B (32x16): lane l holds B[k = 8*(l>>4) + j][n = l&15]
//   C/D      : lane l, reg r holds D[row = 4*(l>>4) + r][col = l&15]

typedef __attribute__((ext_vector_type(4))) float  f32x4;
typedef __attribute__((ext_vector_type(8))) short  bf16x8;
typedef __attribute__((ext_vector_type(4))) unsigned int u32x4;

namespace {
constexpr int B_  = 131072;
constexpr int IN_ = 256;
constexpr int H_  = 58;
constexpr int C_  = 12;

// ws byte offsets (also the LDS image offsets after staging)
constexpr int W1F = 0;        // [ht4][kt8][lane64][j8] bf16 = 32768 B
constexpr int W2F = 32768;    // [ht4][kt2][lane64][j8] bf16 =  8192 B
constexpr int W3F = 40960;    //                                8192 B
constexpr int WOF = 49152;    // [kt2][lane64][j8]      bf16 =  2048 B
constexpr int PAR = 51200;    // 3*64 {A',b'} f32 | bo[16] | {unused x3, So}
constexpr int WS_STAGE = 52816;  // PAR + 404*4, multiple of 16
constexpr int PITCH = 144;    // bounce-tile row pitch (bytes): 128 data + 16 pad
}

__device__ __forceinline__ uint32_t fu(float f) { return __float_as_uint(f); }
__device__ __forceinline__ float    uf(uint32_t u) { return __uint_as_float(u); }
__device__ __forceinline__ float    truncbf(float v) { return uf(fu(v) & 0xffff0000u); }
// pack bf16(a) into low16, bf16(b) into high16 — single v_perm_b32.
__device__ __forceinline__ uint32_t packbf(float a, float b) {
  return __builtin_amdgcn_perm(fu(b), fu(a), 0x07060302u);
}

__device__ __forceinline__ f32x4 MFMA(u32x4 a, bf16x8 b, f32x4 c) {
  union { u32x4 u; bf16x8 s; } ua; ua.u = a;
  return __builtin_amdgcn_mfma_f32_16x16x32_bf16(ua.s, b, c, 0, 0, 0);
}

// ---------------- prep: quantize + fragment-major arrange + param tables ----------------
__global__ void prep_kernel(
    const float* __restrict__ W1, const float* __restrict__ W2,
    const float* __restrict__ W3, const float* __restrict__ Wo,
    const float* __restrict__ g1, const float* __restrict__ b1, const float* __restrict__ s1,
    const float* __restrict__ g2, const float* __restrict__ b2, const float* __restrict__ s2,
    const float* __restrict__ g3, const float* __restrict__ b3, const float* __restrict__ s3,
    const float* __restrict__ bo,
    uint8_t* __restrict__ wsb)
{
  __shared__ float red[1024];
  const int t = threadIdx.x;
  const int blk = blockIdx.x;
  const float* W; int n;
  switch (blk) {
    case 0: W = W1; n = H_ * IN_; break;
    case 1: W = W2; n = H_ * H_;  break;
    case 2: W = W3; n = H_ * H_;  break;
    default: W = Wo; n = C_ * H_; break;
  }
  float m = 0.f;
  for (int i = t; i < n; i += 1024) m = fmaxf(m, fabsf(W[i]));
  red[t] = m;
  __syncthreads();
  for (int s = 512; s > 0; s >>= 1) { if (t < s) red[t] = fmaxf(red[t], red[t + s]); __syncthreads(); }
  const float sw = red[0] / 7.0f;   // per-tensor symmetric, qmax = 7

  float* pp = (float*)(wsb + PAR);

  if (blk == 0) {
    unsigned short* fr = (unsigned short*)(wsb + W1F);
    for (int i = t; i < 16384; i += 1024) {
      const int j = i & 7, ln = (i >> 3) & 63, kt = (i >> 9) & 7, ht = (i >> 12) & 3;
      const int h = (ht << 4) | (ln & 15);
      const int k = (kt << 5) | (((ln >> 4) & 3) << 3) | j;
      float q = 0.f;
      if (h < H_) q = fminf(fmaxf(rintf(W1[h * IN_ + k] / sw), -7.f), 7.f);
      fr[i] = (unsigned short)(fu(q) >> 16);   // small ints exact in bf16
    }
    const float inv = 1.0f / s1[0];
    if (t < 64) {
      pp[2 * t]     = (t < H_) ? sw * g1[t] * inv : 0.f;   // A' = A/s1
      pp[2 * t + 1] = (t < H_) ? b1[t] * inv : 0.f;        // b' = b/s1
    }
  } else if (blk == 1) {
    unsigned short* fr = (unsigned short*)(wsb + W2F);
    for (int i = t; i < 4096; i += 1024) {
      const int j = i & 7, ln = (i >> 3) & 63, kt = (i >> 9) & 1, ht = (i >> 10) & 3;
      const int h = (ht << 4) | (ln & 15);
      const int k = (kt << 5) | (((ln >> 4) & 3) << 3) | j;
      float q = 0.f;
      if (h < H_ && k < H_) q = fminf(fmaxf(rintf(W2[h * H_ + k] / sw), -7.f), 7.f);
      fr[i] = (unsigned short)(fu(q) >> 16);
    }
    const float inv = 1.0f / s2[0];
    if (t < 64) {
      pp[128 + 2 * t]     = (t < H_) ? s1[0] * sw * g2[t] * inv : 0.f;
      pp[128 + 2 * t + 1] = (t < H_) ? b2[t] * inv : 0.f;
    }
  } else if (blk == 2) {
    unsigned short* fr = (unsigned short*)(wsb + W3F);
    for (int i = t; i < 4096; i += 1024) {
      const int j = i & 7, ln = (i >> 3) & 63, kt = (i >> 9) & 1, ht = (i >> 10) & 3;
      const int h = (ht << 4) | (ln & 15);
      const int k = (kt << 5) | (((ln >> 4) & 3) << 3) | j;
      float q = 0.f;
      if (h < H_ && k < H_) q = fminf(fmaxf(rintf(W3[h * H_ + k] / sw), -7.f), 7.f);
      fr[i] = (unsigned short)(fu(q) >> 16);
    }
    const float inv = 1.0f / s3[0];
    if (t < 64) {
      pp[256 + 2 * t]     = (t < H_) ? s2[0] * sw * g3[t] * inv : 0.f;
      pp[256 + 2 * t + 1] = (t < H_) ? b3[t] * inv : 0.f;
    }
  } else {
    unsigned short* fr = (unsigned short*)(wsb + WOF);
    for (int i = t; i < 1024; i += 1024) {
      const int j = i & 7, ln = (i >> 3) & 63, kt = (i >> 9) & 1;
      const int h = ln & 15;
      const int k = (kt << 5) | (((ln >> 4) & 3) << 3) | j;
      float q = 0.f;
      if (h < C_ && k < H_) q = fminf(fmaxf(rintf(Wo[h * H_ + k] / sw), -7.f), 7.f);
      fr[i] = (unsigned short)(fu(q) >> 16);
    }
    if (t < 16) pp[384 + t] = (t < C_) ? bo[t] : 0.f;
    if (t == 0) pp[403] = s3[0] * sw;   // So
  }
}

// ---------------- epilogue: BN+QuantReLU (prescaled) -> bf16 ints -> LDS bounce -> B-frags ----------------
__device__ __forceinline__ void epilog(
    const f32x4 (&acc)[4], const float* pars, int L,
    uint8_t* bw, int g, int c, bf16x8 (&bfr)[2])
{
  const float* pb = pars + L * 128 + 8 * g;   // {A'(h),b'(h)} pairs, h = 16ht+4g+r
#pragma unroll
  for (int ht = 0; ht < 4; ++ht) {
    float q[4];
#pragma unroll
    for (int r = 0; r < 4; ++r) {
      q[r] = __builtin_amdgcn_fmed3f(
          rintf(fmaf(acc[ht][r], pb[32 * ht + 2 * r], pb[32 * ht + 2 * r + 1])),
          0.f, 255.f);
    }
    uint8_t* bp = bw + c * PITCH + 32 * ht + 8 * g;   // row c, bytes 2h..2h+7
    *(uint32_t*)(bp)     = packbf(q[0], q[1]);
    *(uint32_t*)(bp + 4) = packbf(q[2], q[3]);
  }
  // same-wave cross-lane exchange: DS ops from one wave are processed in order
#pragma unroll
  for (int kt = 0; kt < 2; ++kt) {
    const uint8_t* rp = bw + c * PITCH + 64 * kt + 16 * g;  // k = 32kt+8g+j
    union { u32x4 u; bf16x8 s; } uv;
    uv.u = *(const u32x4*)rp;
    bfr[kt] = uv.s;
  }
}

__global__ __launch_bounds__(512, 1) void fused_mfma_kernel(
    const float* __restrict__ x, const uint8_t* __restrict__ wsb,
    float* __restrict__ out)
{
  // LDS: ws image (52.8K) + x double-buffer (64K) + bounce (18K) = 136.8K -> 1 block/CU.
  __shared__ __align__(16) uint8_t wlds[WS_STAGE];
  __shared__ __align__(16) float   xs[2][8192];          // 2 x (8 waves x 16 rows x 64 f32)
  __shared__ __align__(16) uint8_t bnc[8][16 * PITCH];   // per-wave bounce tiles

  const int t = threadIdx.x;
  const int w = t >> 6, l = t & 63, g = (l >> 4) & 3, c = l & 15;
  const size_t rowbase = (size_t)blockIdx.x * 128;

  // Stage ws -> LDS: 7 chunks of 8KB (512 lanes x 16B), linear both sides.
#pragma unroll
  for (int i = 0; i < 7; ++i) {
    const int off = i * 8192 + t * 16;
    if (off < WS_STAGE) {
      __builtin_amdgcn_global_load_lds(
          (const __attribute__((address_space(1))) void*)(wsb + off),
          (__attribute__((address_space(3))) void*)(wlds + off), 16, 0, 0);
    }
  }

  // Stage one 64-float chunk of this wave's 16 rows into its own LDS slice.
  // DMA i covers LDS rows 4i..4i+3 linearly (lane l -> row 4i+(l>>4), slot l&15);
  // global source slot is (l&15) ^ row — read side undoes the XOR (rule #21,
  // verified correct in round 9's passing run).
#define STAGE(ch_, buf_)                                                             \
  {                                                                                  \
    _Pragma("unroll")                                                                \
    for (int i = 0; i < 4; ++i) {                                                    \
      const int row16 = 4 * i + g;                                                   \
      const int slot_src = (l & 15) ^ row16;                                         \
      const float* src = x + (rowbase + 16 * w + row16) * IN_                        \
                           + (ch_) * 64 + 4 * slot_src;                              \
      void* dst = (char*)&xs[buf_][0] + w * 4096 + i * 1024;                         \
      __builtin_amdgcn_global_load_lds(                                              \
          (const __attribute__((address_space(1))) void*)src,                        \
          (__attribute__((address_space(3))) void*)dst, 16, 0, 0);                   \
    }                                                                                \
  }

  STAGE(0, 0);
  __syncthreads();   // drains vmcnt: ws image + chunk 0 ready

  const float* pars = (const float*)(wlds + PAR);
  const float So = pars[403];

  f32x4 acc[4];
#pragma unroll
  for (int ht = 0; ht < 4; ++ht) acc[ht] = f32x4{0.f, 0.f, 0.f, 0.f};

  // ---- Layer 1: 4 chunks x 2 k-tiles, 3 exact bf16 limbs, DMA double-buffer ----
#pragma unroll
  for (int ch = 0; ch < 4; ++ch) {
    if (ch < 3) STAGE(ch + 1, (ch + 1) & 1);
    // wait for this chunk's 4 DMAs; the newest 4 (next chunk) stay in flight
    asm volatile("s_waitcnt vmcnt(4)" ::: "memory");

    const char* xb = (const char*)&xs[ch & 1][0] + w * 4096 + c * 256;  // row c slice
#pragma unroll
    for (int s2 = 0; s2 < 2; ++s2) {
      const int s = 2 * ch + s2;   // global k-tile index 0..7
      u32x4 wf[4];
#pragma unroll
      for (int ht = 0; ht < 4; ++ht)
        wf[ht] = *(const u32x4*)(wlds + W1F + (size_t)(((ht * 8 + s) * 64) + l) * 16);

      // wanted global 16B-slots 8*s2+2g, +1 of row c  ->  LDS slot ^= c
      const int w0 = (128 * s2 + 32 * g)      ^ (c << 4);
      const int w1 = (128 * s2 + 32 * g + 16) ^ (c << 4);
      const f32x4 e0 = *(const f32x4*)(xb + w0);
      const f32x4 e1 = *(const f32x4*)(xb + w1);
      const float el[8] = {e0.x, e0.y, e0.z, e0.w, e1.x, e1.y, e1.z, e1.w};

      float d[8], e2[8];
#pragma unroll
      for (int q = 0; q < 8; ++q) d[q] = el[q] - truncbf(el[q]);   // exact
#pragma unroll
      for (int q = 0; q < 8; ++q) e2[q] = d[q] - truncbf(d[q]);    // exact

      union { uint32_t u[4]; bf16x8 v; } bh, bl1, bl2;
#pragma unroll
      for (int q = 0; q < 4; ++q) {
        bh.u[q]  = packbf(el[2 * q], el[2 * q + 1]);
        bl1.u[q] = packbf(d[2 * q],  d[2 * q + 1]);
        bl2.u[q] = packbf(e2[2 * q], e2[2 * q + 1]);
      }
#pragma unroll
      for (int ht = 0; ht < 4; ++ht) acc[ht] = MFMA(wf[ht], bh.v,  acc[ht]);
#pragma unroll
      for (int ht = 0; ht < 4; ++ht) acc[ht] = MFMA(wf[ht], bl1.v, acc[ht]);
#pragma unroll
      for (int ht = 0; ht < 4; ++ht) acc[ht] = MFMA(wf[ht], bl2.v, acc[ht]);
    }
  }
#undef STAGE

  uint8_t* bw = &bnc[w][0];
  bf16x8 bfr[2];

  // ---- Layer 2 ----
  epilog(acc, pars, 0, bw, g, c, bfr);
  f32x4 a2[4];
#pragma unroll
  for (int ht = 0; ht < 4; ++ht) a2[ht] = f32x4{0.f, 0.f, 0.f, 0.f};
#pragma unroll
  for (int kt = 0; kt < 2; ++kt) {
#pragma unroll
    for (int ht = 0; ht < 4; ++ht) {
      const u32x4 wf = *(const u32x4*)(wlds + W2F + (size_t)(((ht * 2 + kt) * 64) + l) * 16);
      a2[ht] = MFMA(wf, bfr[kt], a2[ht]);
    }
  }

  // ---- Layer 3 ----
  epilog(a2, pars, 1, bw, g, c, bfr);
  f32x4 a3[4];
#pragma unroll
  for (int ht = 0; ht < 4; ++ht) a3[ht] = f32x4{0.f, 0.f, 0.f, 0.f};
#pragma unroll
  for (int kt = 0; kt < 2; ++kt) {
#pragma unroll
    for (int ht = 0; ht < 4; ++ht) {
      const u32x4 wf = *(const u32x4*)(wlds + W3F + (size_t)(((ht * 2 + kt) * 64) + l) * 16);
      a3[ht] = MFMA(wf, bfr[kt], a3[ht]);
    }
  }

  // ---- Output layer ----
  epilog(a3, pars, 2, bw, g, c, bfr);
  f32x4 ao = f32x4{0.f, 0.f, 0.f, 0.f};
#pragma unroll
  for (int kt = 0; kt < 2; ++kt) {
    const u32x4 wf = *(const u32x4*)(wlds + WOF + (size_t)((kt * 64) + l) * 16);
    ao = MFMA(wf, bfr[kt], ao);
  }

  const float bo0 = pars[384 + 4 * g + 0];
  const float bo1 = pars[384 + 4 * g + 1];
  const float bo2 = pars[384 + 4 * g + 2];
  const float bo3 = pars[384 + 4 * g + 3];
  f32x4 o;
  o.x = fmaf(ao.x, So, bo0);
  o.y = fmaf(ao.y, So, bo1);
  o.z = fmaf(ao.z, So, bo2);
  o.w = fmaf(ao.w, So, bo3);
  if (g < 3)  // out channels 4g..4g+3; only 0..11 exist
    *(f32x4*)(out + (rowbase + 16 * w + c) * C_ + 4 * g) = o;
}

extern "C" void kernel_launch(void* const* d_in, const int* in_sizes, int n_in,
                              void* d_out, int out_size, void* d_ws, size_t ws_size,
                              hipStream_t stream) {
  // 0:x 1:W1 2:g1 3:b1 4:s1 5:W2 6:g2 7:b2 8:s2 9:W3 10:g3 11:b3 12:s3 13:Wo 14:bo
  const float* x  = (const float*)d_in[0];
  const float* W1 = (const float*)d_in[1];
  const float* g1 = (const float*)d_in[2];
  const float* b1 = (const float*)d_in[3];
  const float* s1 = (const float*)d_in[4];
  const float* W2 = (const float*)d_in[5];
  const float* g2 = (const float*)d_in[6];
  const float* b2 = (const float*)d_in[7];
  const float* s2 = (const float*)d_in[8];
  const float* W3 = (const float*)d_in[9];
  const float* g3 = (const float*)d_in[10];
  const float* b3 = (const float*)d_in[11];
  const float* s3 = (const float*)d_in[12];
  const float* Wo = (const float*)d_in[13];
  const float* bo = (const float*)d_in[14];

  uint8_t* ws = (uint8_t*)d_ws;
  float* out = (float*)d_out;

  prep_kernel<<<4, 1024, 0, stream>>>(W1, W2, W3, Wo, g1, b1, s1, g2, b2, s2,
                                      g3, b3, s3, bo, ws);
  fused_mfma_kernel<<<B_ / 128, 512, 0, stream>>>(x, ws, out);
}

// Round 15
// 42.212 us; speedup vs baseline: 1.1662x; 1.0625x over previous
//
#include <hip/hip_runtime.h>
#include <stdint.h>

// QuantDenseModelLarge on gfx950 — MFMA formulation.
// Round 15 = round 12 (41.0 µs, best) with 1024-thread fused blocks (512 blocks,
// 16 waves). ws staging + barrier amortized over 2x rows; occupancy unchanged
// (16 waves/CU = 4/SIMD, LDS 89.7KB -> 1 block/CU). Controlled A/B vs r12.
// r13/r14 lesson: x-path (burst granularity, cache residency, DMA concurrency)
// is NOT the limiter; wins have come only from amortizing per-block memory
// overheads (weights r10: -15us, waves r11: -4us).
//
// Exact identities:
//   quant weights = qw * sw, qw int in [-7,7]  -> exact in bf16
//   QuantReLU out = qa * s,  qa int in [0,255] -> exact in bf16
//   layers 2/3/out: D = sum(qa*qw) exact in f32; y = D*(s*sw)
//   layer 1: x == hi + lo1 + lo2 EXACTLY (3 bf16 truncation limbs cover 24 bits)
//   rint(max(y,0)) == med3(rint(y), 0, 255) for the clamp (rint monotone)
//
// MFMA layout (hardware-verified via learn_hip m89/m92 ref-checked GEMMs):
//   A (16x32): lane l holds A[m = l&15][k = 8*(l>>4) + j], j=0..7
//   B (32x16): lane l holds B[k = 8*(l>>4) + j][n = l&15]
//   C/D      : lane l, reg r holds D[row = 4*(l>>4) + r][col = l&15]

typedef __attribute__((ext_vector_type(4))) float  f32x4;
typedef __attribute__((ext_vector_type(8))) short  bf16x8;
typedef __attribute__((ext_vector_type(4))) unsigned int u32x4;

namespace {
constexpr int B_  = 131072;
constexpr int IN_ = 256;
constexpr int H_  = 58;
constexpr int C_  = 12;

// ws byte offsets (also the LDS image offsets after staging)
constexpr int W1F = 0;        // [ht4][kt8][lane64][j8] bf16 = 32768 B
constexpr int W2F = 32768;    // [ht4][kt2][lane64][j8] bf16 =  8192 B
constexpr int W3F = 40960;    //                                8192 B
constexpr int WOF = 49152;    // [kt2][lane64][j8]      bf16 =  2048 B
constexpr int PAR = 51200;    // 3*64 {A',b'} f32 | bo[16] | {unused x3, So}
constexpr int WS_STAGE = 52816;  // PAR + 404*4, multiple of 16
constexpr int PITCH = 144;    // bounce-tile row pitch (bytes): 128 data + 16 pad
}

__device__ __forceinline__ uint32_t fu(float f) { return __float_as_uint(f); }
__device__ __forceinline__ float    uf(uint32_t u) { return __uint_as_float(u); }
__device__ __forceinline__ float    truncbf(float v) { return uf(fu(v) & 0xffff0000u); }
// pack bf16(a) into low16, bf16(b) into high16 — single v_perm_b32.
__device__ __forceinline__ uint32_t packbf(float a, float b) {
  return __builtin_amdgcn_perm(fu(b), fu(a), 0x07060302u);
}

__device__ __forceinline__ f32x4 MFMA(u32x4 a, bf16x8 b, f32x4 c) {
  union { u32x4 u; bf16x8 s; } ua; ua.u = a;
  return __builtin_amdgcn_mfma_f32_16x16x32_bf16(ua.s, b, c, 0, 0, 0);
}

// ---------------- prep: quantize + fragment-major arrange + param tables ----------------
__global__ void prep_kernel(
    const float* __restrict__ W1, const float* __restrict__ W2,
    const float* __restrict__ W3, const float* __restrict__ Wo,
    const float* __restrict__ g1, const float* __restrict__ b1, const float* __restrict__ s1,
    const float* __restrict__ g2, const float* __restrict__ b2, const float* __restrict__ s2,
    const float* __restrict__ g3, const float* __restrict__ b3, const float* __restrict__ s3,
    const float* __restrict__ bo,
    uint8_t* __restrict__ wsb)
{
  __shared__ float red[1024];
  const int t = threadIdx.x;
  const int blk = blockIdx.x;
  const float* W; int n;
  switch (blk) {
    case 0: W = W1; n = H_ * IN_; break;
    case 1: W = W2; n = H_ * H_;  break;
    case 2: W = W3; n = H_ * H_;  break;
    default: W = Wo; n = C_ * H_; break;
  }
  float m = 0.f;
  for (int i = t; i < n; i += 1024) m = fmaxf(m, fabsf(W[i]));
  red[t] = m;
  __syncthreads();
  for (int s = 512; s > 0; s >>= 1) { if (t < s) red[t] = fmaxf(red[t], red[t + s]); __syncthreads(); }
  const float sw = red[0] / 7.0f;   // per-tensor symmetric, qmax = 7

  float* pp = (float*)(wsb + PAR);

  if (blk == 0) {
    unsigned short* fr = (unsigned short*)(wsb + W1F);
    for (int i = t; i < 16384; i += 1024) {
      const int j = i & 7, ln = (i >> 3) & 63, kt = (i >> 9) & 7, ht = (i >> 12) & 3;
      const int h = (ht << 4) | (ln & 15);
      const int k = (kt << 5) | (((ln >> 4) & 3) << 3) | j;
      float q = 0.f;
      if (h < H_) q = fminf(fmaxf(rintf(W1[h * IN_ + k] / sw), -7.f), 7.f);
      fr[i] = (unsigned short)(fu(q) >> 16);   // small ints exact in bf16
    }
    const float inv = 1.0f / s1[0];
    if (t < 64) {
      pp[2 * t]     = (t < H_) ? sw * g1[t] * inv : 0.f;   // A' = A/s1
      pp[2 * t + 1] = (t < H_) ? b1[t] * inv : 0.f;        // b' = b/s1
    }
  } else if (blk == 1) {
    unsigned short* fr = (unsigned short*)(wsb + W2F);
    for (int i = t; i < 4096; i += 1024) {
      const int j = i & 7, ln = (i >> 3) & 63, kt = (i >> 9) & 1, ht = (i >> 10) & 3;
      const int h = (ht << 4) | (ln & 15);
      const int k = (kt << 5) | (((ln >> 4) & 3) << 3) | j;
      float q = 0.f;
      if (h < H_ && k < H_) q = fminf(fmaxf(rintf(W2[h * H_ + k] / sw), -7.f), 7.f);
      fr[i] = (unsigned short)(fu(q) >> 16);
    }
    const float inv = 1.0f / s2[0];
    if (t < 64) {
      pp[128 + 2 * t]     = (t < H_) ? s1[0] * sw * g2[t] * inv : 0.f;
      pp[128 + 2 * t + 1] = (t < H_) ? b2[t] * inv : 0.f;
    }
  } else if (blk == 2) {
    unsigned short* fr = (unsigned short*)(wsb + W3F);
    for (int i = t; i < 4096; i += 1024) {
      const int j = i & 7, ln = (i >> 3) & 63, kt = (i >> 9) & 1, ht = (i >> 10) & 3;
      const int h = (ht << 4) | (ln & 15);
      const int k = (kt << 5) | (((ln >> 4) & 3) << 3) | j;
      float q = 0.f;
      if (h < H_ && k < H_) q = fminf(fmaxf(rintf(W3[h * H_ + k] / sw), -7.f), 7.f);
      fr[i] = (unsigned short)(fu(q) >> 16);
    }
    const float inv = 1.0f / s3[0];
    if (t < 64) {
      pp[256 + 2 * t]     = (t < H_) ? s2[0] * sw * g3[t] * inv : 0.f;
      pp[256 + 2 * t + 1] = (t < H_) ? b3[t] * inv : 0.f;
    }
  } else {
    unsigned short* fr = (unsigned short*)(wsb + WOF);
    for (int i = t; i < 1024; i += 1024) {
      const int j = i & 7, ln = (i >> 3) & 63, kt = (i >> 9) & 1;
      const int h = ln & 15;
      const int k = (kt << 5) | (((ln >> 4) & 3) << 3) | j;
      float q = 0.f;
      if (h < C_ && k < H_) q = fminf(fmaxf(rintf(Wo[h * H_ + k] / sw), -7.f), 7.f);
      fr[i] = (unsigned short)(fu(q) >> 16);
    }
    if (t < 16) pp[384 + t] = (t < C_) ? bo[t] : 0.f;
    if (t == 0) pp[403] = s3[0] * sw;   // So
  }
}

// ---------------- epilogue: BN+QuantReLU (prescaled) -> bf16 ints -> LDS bounce -> B-frags ----------------
__device__ __forceinline__ void epilog(
    const f32x4 (&acc)[4], const float* pars, int L,
    uint8_t* bw, int g, int c, bf16x8 (&bfr)[2])
{
  const float* pb = pars + L * 128 + 8 * g;   // {A'(h),b'(h)} pairs, h = 16ht+4g+r
#pragma unroll
  for (int ht = 0; ht < 4; ++ht) {
    float q[4];
#pragma unroll
    for (int r = 0; r < 4; ++r) {
      q[r] = __builtin_amdgcn_fmed3f(
          rintf(fmaf(acc[ht][r], pb[32 * ht + 2 * r], pb[32 * ht + 2 * r + 1])),
          0.f, 255.f);
    }
    uint8_t* bp = bw + c * PITCH + 32 * ht + 8 * g;   // row c, bytes 2h..2h+7
    *(uint32_t*)(bp)     = packbf(q[0], q[1]);
    *(uint32_t*)(bp + 4) = packbf(q[2], q[3]);
  }
  // same-wave cross-lane exchange: DS ops from one wave are processed in order
#pragma unroll
  for (int kt = 0; kt < 2; ++kt) {
    const uint8_t* rp = bw + c * PITCH + 64 * kt + 16 * g;  // k = 32kt+8g+j
    union { u32x4 u; bf16x8 s; } uv;
    uv.u = *(const u32x4*)rp;
    bfr[kt] = uv.s;
  }
}

__global__ __launch_bounds__(1024, 4) void fused_mfma_kernel(
    const float* __restrict__ x, const uint8_t* __restrict__ wsb,
    float* __restrict__ out)
{
  // LDS: ws image (52.8K) + 16 bounce tiles (36.9K) = 89.7K -> 1 block/CU,
  // 16 waves/CU = 4/SIMD (same occupancy as r12, half the staging events).
  __shared__ __align__(16) uint8_t wlds[WS_STAGE];
  __shared__ __align__(16) uint8_t bnc[16][16 * PITCH];  // per-wave bounce tiles

  const int t = threadIdx.x;
  const int w = t >> 6, l = t & 63, g = (l >> 4) & 3, c = l & 15;
  const size_t rowbase = (size_t)blockIdx.x * 256;

  // Stage ws -> LDS: 4 chunks of 16KB (1024 lanes x 16B), linear both sides.
#pragma unroll
  for (int i = 0; i < 4; ++i) {
    const int off = i * 16384 + t * 16;
    if (off < WS_STAGE) {
      __builtin_amdgcn_global_load_lds(
          (const __attribute__((address_space(1))) void*)(wsb + off),
          (__attribute__((address_space(3))) void*)(wlds + off), 16, 0, 0);
    }
  }

  // this lane's batch row (B-fragment n = l&15); k-slice owned: 8g..8g+7 (+32s)
  const float* __restrict__ xrow = x + (rowbase + 16 * w + c) * IN_;

  // Hoist k-tiles 0/1 x loads above the barrier: the barrier's vmcnt(0) drain
  // completes them alongside the staging DMAs -> no post-barrier stall.
  f32x4 xpre[4];
  xpre[0] = *(const f32x4*)(xrow + 8 * g);
  xpre[1] = *(const f32x4*)(xrow + 8 * g + 4);
  xpre[2] = *(const f32x4*)(xrow + 32 + 8 * g);
  xpre[3] = *(const f32x4*)(xrow + 32 + 8 * g + 4);

  __syncthreads();   // drains vmcnt -> staged image + xpre ready

  const float* pars = (const float*)(wlds + PAR);
  const float So = pars[403];

  f32x4 acc[4];
#pragma unroll
  for (int ht = 0; ht < 4; ++ht) acc[ht] = f32x4{0.f, 0.f, 0.f, 0.f};

  // ---- Layer 1: 8 k-tiles of 32, 3 exact bf16 limbs; A-frags via ds_read_b128 ----
#pragma unroll
  for (int s = 0; s < 8; ++s) {
    u32x4 wf[4];
#pragma unroll
    for (int ht = 0; ht < 4; ++ht)
      wf[ht] = *(const u32x4*)(wlds + W1F + (size_t)(((ht * 8 + s) * 64) + l) * 16);

    const f32x4 e0 = (s == 0) ? xpre[0] : (s == 1) ? xpre[2]
                     : *(const f32x4*)(xrow + 32 * s + 8 * g);
    const f32x4 e1 = (s == 0) ? xpre[1] : (s == 1) ? xpre[3]
                     : *(const f32x4*)(xrow + 32 * s + 8 * g + 4);
    const float el[8] = {e0.x, e0.y, e0.z, e0.w, e1.x, e1.y, e1.z, e1.w};

    float d[8], e2[8];
#pragma unroll
    for (int q = 0; q < 8; ++q) d[q] = el[q] - truncbf(el[q]);   // exact
#pragma unroll
    for (int q = 0; q < 8; ++q) e2[q] = d[q] - truncbf(d[q]);    // exact

    union { uint32_t u[4]; bf16x8 v; } bh, bl1, bl2;
#pragma unroll
    for (int q = 0; q < 4; ++q) {
      bh.u[q]  = packbf(el[2 * q], el[2 * q + 1]);
      bl1.u[q] = packbf(d[2 * q],  d[2 * q + 1]);
      bl2.u[q] = packbf(e2[2 * q], e2[2 * q + 1]);
    }
#pragma unroll
    for (int ht = 0; ht < 4; ++ht) acc[ht] = MFMA(wf[ht], bh.v,  acc[ht]);
#pragma unroll
    for (int ht = 0; ht < 4; ++ht) acc[ht] = MFMA(wf[ht], bl1.v, acc[ht]);
#pragma unroll
    for (int ht = 0; ht < 4; ++ht) acc[ht] = MFMA(wf[ht], bl2.v, acc[ht]);
  }

  uint8_t* bw = &bnc[w][0];
  bf16x8 bfr[2];

  // ---- Layer 2 ----
  epilog(acc, pars, 0, bw, g, c, bfr);
  f32x4 a2[4];
#pragma unroll
  for (int ht = 0; ht < 4; ++ht) a2[ht] = f32x4{0.f, 0.f, 0.f, 0.f};
#pragma unroll
  for (int kt = 0; kt < 2; ++kt) {
#pragma unroll
    for (int ht = 0; ht < 4; ++ht) {
      const u32x4 wf = *(const u32x4*)(wlds + W2F + (size_t)(((ht * 2 + kt) * 64) + l) * 16);
      a2[ht] = MFMA(wf, bfr[kt], a2[ht]);
    }
  }

  // ---- Layer 3 ----
  epilog(a2, pars, 1, bw, g, c, bfr);
  f32x4 a3[4];
#pragma unroll
  for (int ht = 0; ht < 4; ++ht) a3[ht] = f32x4{0.f, 0.f, 0.f, 0.f};
#pragma unroll
  for (int kt = 0; kt < 2; ++kt) {
#pragma unroll
    for (int ht = 0; ht < 4; ++ht) {
      const u32x4 wf = *(const u32x4*)(wlds + W3F + (size_t)(((ht * 2 + kt) * 64) + l) * 16);
      a3[ht] = MFMA(wf, bfr[kt], a3[ht]);
    }
  }

  // ---- Output layer ----
  epilog(a3, pars, 2, bw, g, c, bfr);
  f32x4 ao = f32x4{0.f, 0.f, 0.f, 0.f};
#pragma unroll
  for (int kt = 0; kt < 2; ++kt) {
    const u32x4 wf = *(const u32x4*)(wlds + WOF + (size_t)((kt * 64) + l) * 16);
    ao = MFMA(wf, bfr[kt], ao);
  }

  const float bo0 = pars[384 + 4 * g + 0];
  const float bo1 = pars[384 + 4 * g + 1];
  const float bo2 = pars[384 + 4 * g + 2];
  const float bo3 = pars[384 + 4 * g + 3];
  f32x4 o;
  o.x = fmaf(ao.x, So, bo0);
  o.y = fmaf(ao.y, So, bo1);
  o.z = fmaf(ao.z, So, bo2);
  o.w = fmaf(ao.w, So, bo3);
  if (g < 3)  // out channels 4g..4g+3; only 0..11 exist
    *(f32x4*)(out + (rowbase + 16 * w + c) * C_ + 4 * g) = o;
}

extern "C" void kernel_launch(void* const* d_in, const int* in_sizes, int n_in,
                              void* d_out, int out_size, void* d_ws, size_t ws_size,
                              hipStream_t stream) {
  // 0:x 1:W1 2:g1 3:b1 4:s1 5:W2 6:g2 7:b2 8:s2 9:W3 10:g3 11:b3 12:s3 13:Wo 14:bo
  const float* x  = (const float*)d_in[0];
  const float* W1 = (const float*)d_in[1];
  const float* g1 = (const float*)d_in[2];
  const float* b1 = (const float*)d_in[3];
  const float* s1 = (const float*)d_in[4];
  const float* W2 = (const float*)d_in[5];
  const float* g2 = (const float*)d_in[6];
  const float* b2 = (const float*)d_in[7];
  const float* s2 = (const float*)d_in[8];
  const float* W3 = (const float*)d_in[9];
  const float* g3 = (const float*)d_in[10];
  const float* b3 = (const float*)d_in[11];
  const float* s3 = (const float*)d_in[12];
  const float* Wo = (const float*)d_in[13];
  const float* bo = (const float*)d_in[14];

  uint8_t* ws = (uint8_t*)d_ws;
  float* out = (float*)d_out;

  prep_kernel<<<4, 1024, 0, stream>>>(W1, W2, W3, Wo, g1, b1, s1, g2, b2, s2,
                                      g3, b3, s3, bo, ws);
  fused_mfma_kernel<<<B_ / 256, 1024, 0, stream>>>(x, ws, out);
}

// Round 16
// 41.129 us; speedup vs baseline: 1.1969x; 1.0263x over previous
//
#include <hip/hip_runtime.h>
#include <stdint.h>

// QuantDenseModelLarge on gfx950 — MFMA formulation.
// Round 16 = round 12 (41.0 µs, best) + 4-tile rolling x register pipeline.
// Theory: per-CU pipe work sums to ~27K cy but runtime is ~98K cy -> ~70%
// simultaneous-stall = exposed L3 latency (x is L3-resident, L2-missing:
// 16.7MB/XCD slice > 4MB L2; ~500-600cy/load) in layer 1's 8-tile load-use
// chain. Fix: xr[4 tiles] rolling pipeline — tiles 0-3 preloaded BEFORE the
// staging barrier (latency hides under vmcnt(0) drain), tile s+4 issued as
// tile s is consumed -> issue-to-use distance ~4 tiles (~1K cy) > L3 latency,
// ~2 exposed fills/wave instead of ~8. +32 VGPR, est. total ~120 < 128 cliff.
//
// Exact identities:
//   quant weights = qw * sw, qw int in [-7,7]  -> exact in bf16
//   QuantReLU out = qa * s,  qa int in [0,255] -> exact in bf16
//   layers 2/3/out: D = sum(qa*qw) exact in f32; y = D*(s*sw)
//   layer 1: x == hi + lo1 + lo2 EXACTLY (3 bf16 truncation limbs cover 24 bits)
//   rint(max(y,0)) == med3(rint(y), 0, 255) for the clamp (rint monotone)
//
// MFMA layout (hardware-verified via learn_hip m89/m92 ref-checked GEMMs):
//   A (16x32): lane l holds A[m = l&15][k = 8*(l>>4) + j], j=0..7
//   B (32x16): lane l holds B[k = 8*(l>>4) + j][n = l&15]
//   C/D      : lane l, reg r holds D[row = 4*(l>>4) + r][col = l&15]

typedef __attribute__((ext_vector_type(4))) float  f32x4;
typedef __attribute__((ext_vector_type(8))) short  bf16x8;
typedef __attribute__((ext_vector_type(4))) unsigned int u32x4;

namespace {
constexpr int B_  = 131072;
constexpr int IN_ = 256;
constexpr int H_  = 58;
constexpr int C_  = 12;

// ws byte offsets (also the LDS image offsets after staging)
constexpr int W1F = 0;        // [ht4][kt8][lane64][j8] bf16 = 32768 B
constexpr int W2F = 32768;    // [ht4][kt2][lane64][j8] bf16 =  8192 B
constexpr int W3F = 40960;    //                                8192 B
constexpr int WOF = 49152;    // [kt2][lane64][j8]      bf16 =  2048 B
constexpr int PAR = 51200;    // 3*64 {A',b'} f32 | bo[16] | {unused x3, So}
constexpr int WS_STAGE = 52816;  // PAR + 404*4, multiple of 16
constexpr int PITCH = 144;    // bounce-tile row pitch (bytes): 128 data + 16 pad
}

__device__ __forceinline__ uint32_t fu(float f) { return __float_as_uint(f); }
__device__ __forceinline__ float    uf(uint32_t u) { return __uint_as_float(u); }
__device__ __forceinline__ float    truncbf(float v) { return uf(fu(v) & 0xffff0000u); }
// pack bf16(a) into low16, bf16(b) into high16 — single v_perm_b32.
__device__ __forceinline__ uint32_t packbf(float a, float b) {
  return __builtin_amdgcn_perm(fu(b), fu(a), 0x07060302u);
}

__device__ __forceinline__ f32x4 MFMA(u32x4 a, bf16x8 b, f32x4 c) {
  union { u32x4 u; bf16x8 s; } ua; ua.u = a;
  return __builtin_amdgcn_mfma_f32_16x16x32_bf16(ua.s, b, c, 0, 0, 0);
}

// ---------------- prep: quantize + fragment-major arrange + param tables ----------------
__global__ void prep_kernel(
    const float* __restrict__ W1, const float* __restrict__ W2,
    const float* __restrict__ W3, const float* __restrict__ Wo,
    const float* __restrict__ g1, const float* __restrict__ b1, const float* __restrict__ s1,
    const float* __restrict__ g2, const float* __restrict__ b2, const float* __restrict__ s2,
    const float* __restrict__ g3, const float* __restrict__ b3, const float* __restrict__ s3,
    const float* __restrict__ bo,
    uint8_t* __restrict__ wsb)
{
  __shared__ float red[1024];
  const int t = threadIdx.x;
  const int blk = blockIdx.x;
  const float* W; int n;
  switch (blk) {
    case 0: W = W1; n = H_ * IN_; break;
    case 1: W = W2; n = H_ * H_;  break;
    case 2: W = W3; n = H_ * H_;  break;
    default: W = Wo; n = C_ * H_; break;
  }
  float m = 0.f;
  for (int i = t; i < n; i += 1024) m = fmaxf(m, fabsf(W[i]));
  red[t] = m;
  __syncthreads();
  for (int s = 512; s > 0; s >>= 1) { if (t < s) red[t] = fmaxf(red[t], red[t + s]); __syncthreads(); }
  const float sw = red[0] / 7.0f;   // per-tensor symmetric, qmax = 7

  float* pp = (float*)(wsb + PAR);

  if (blk == 0) {
    unsigned short* fr = (unsigned short*)(wsb + W1F);
    for (int i = t; i < 16384; i += 1024) {
      const int j = i & 7, ln = (i >> 3) & 63, kt = (i >> 9) & 7, ht = (i >> 12) & 3;
      const int h = (ht << 4) | (ln & 15);
      const int k = (kt << 5) | (((ln >> 4) & 3) << 3) | j;
      float q = 0.f;
      if (h < H_) q = fminf(fmaxf(rintf(W1[h * IN_ + k] / sw), -7.f), 7.f);
      fr[i] = (unsigned short)(fu(q) >> 16);   // small ints exact in bf16
    }
    const float inv = 1.0f / s1[0];
    if (t < 64) {
      pp[2 * t]     = (t < H_) ? sw * g1[t] * inv : 0.f;   // A' = A/s1
      pp[2 * t + 1] = (t < H_) ? b1[t] * inv : 0.f;        // b' = b/s1
    }
  } else if (blk == 1) {
    unsigned short* fr = (unsigned short*)(wsb + W2F);
    for (int i = t; i < 4096; i += 1024) {
      const int j = i & 7, ln = (i >> 3) & 63, kt = (i >> 9) & 1, ht = (i >> 10) & 3;
      const int h = (ht << 4) | (ln & 15);
      const int k = (kt << 5) | (((ln >> 4) & 3) << 3) | j;
      float q = 0.f;
      if (h < H_ && k < H_) q = fminf(fmaxf(rintf(W2[h * H_ + k] / sw), -7.f), 7.f);
      fr[i] = (unsigned short)(fu(q) >> 16);
    }
    const float inv = 1.0f / s2[0];
    if (t < 64) {
      pp[128 + 2 * t]     = (t < H_) ? s1[0] * sw * g2[t] * inv : 0.f;
      pp[128 + 2 * t + 1] = (t < H_) ? b2[t] * inv : 0.f;
    }
  } else if (blk == 2) {
    unsigned short* fr = (unsigned short*)(wsb + W3F);
    for (int i = t; i < 4096; i += 1024) {
      const int j = i & 7, ln = (i >> 3) & 63, kt = (i >> 9) & 1, ht = (i >> 10) & 3;
      const int h = (ht << 4) | (ln & 15);
      const int k = (kt << 5) | (((ln >> 4) & 3) << 3) | j;
      float q = 0.f;
      if (h < H_ && k < H_) q = fminf(fmaxf(rintf(W3[h * H_ + k] / sw), -7.f), 7.f);
      fr[i] = (unsigned short)(fu(q) >> 16);
    }
    const float inv = 1.0f / s3[0];
    if (t < 64) {
      pp[256 + 2 * t]     = (t < H_) ? s2[0] * sw * g3[t] * inv : 0.f;
      pp[256 + 2 * t + 1] = (t < H_) ? b3[t] * inv : 0.f;
    }
  } else {
    unsigned short* fr = (unsigned short*)(wsb + WOF);
    for (int i = t; i < 1024; i += 1024) {
      const int j = i & 7, ln = (i >> 3) & 63, kt = (i >> 9) & 1;
      const int h = ln & 15;
      const int k = (kt << 5) | (((ln >> 4) & 3) << 3) | j;
      float q = 0.f;
      if (h < C_ && k < H_) q = fminf(fmaxf(rintf(Wo[h * H_ + k] / sw), -7.f), 7.f);
      fr[i] = (unsigned short)(fu(q) >> 16);
    }
    if (t < 16) pp[384 + t] = (t < C_) ? bo[t] : 0.f;
    if (t == 0) pp[403] = s3[0] * sw;   // So
  }
}

// ---------------- epilogue: BN+QuantReLU (prescaled) -> bf16 ints -> LDS bounce -> B-frags ----------------
__device__ __forceinline__ void epilog(
    const f32x4 (&acc)[4], const float* pars, int L,
    uint8_t* bw, int g, int c, bf16x8 (&bfr)[2])
{
  const float* pb = pars + L * 128 + 8 * g;   // {A'(h),b'(h)} pairs, h = 16ht+4g+r
#pragma unroll
  for (int ht = 0; ht < 4; ++ht) {
    float q[4];
#pragma unroll
    for (int r = 0; r < 4; ++r) {
      q[r] = __builtin_amdgcn_fmed3f(
          rintf(fmaf(acc[ht][r], pb[32 * ht + 2 * r], pb[32 * ht + 2 * r + 1])),
          0.f, 255.f);
    }
    uint8_t* bp = bw + c * PITCH + 32 * ht + 8 * g;   // row c, bytes 2h..2h+7
    *(uint32_t*)(bp)     = packbf(q[0], q[1]);
    *(uint32_t*)(bp + 4) = packbf(q[2], q[3]);
  }
  // same-wave cross-lane exchange: DS ops from one wave are processed in order
#pragma unroll
  for (int kt = 0; kt < 2; ++kt) {
    const uint8_t* rp = bw + c * PITCH + 64 * kt + 16 * g;  // k = 32kt+8g+j
    union { u32x4 u; bf16x8 s; } uv;
    uv.u = *(const u32x4*)rp;
    bfr[kt] = uv.s;
  }
}

__global__ __launch_bounds__(512, 4) void fused_mfma_kernel(
    const float* __restrict__ x, const uint8_t* __restrict__ wsb,
    float* __restrict__ out)
{
  // Entire ws image (weight fragments + params) staged once per block.
  __shared__ __align__(16) uint8_t wlds[WS_STAGE];
  __shared__ __align__(16) uint8_t bnc[8][16 * PITCH];  // per-wave bounce tiles

  const int t = threadIdx.x;
  const int w = t >> 6, l = t & 63, g = (l >> 4) & 3, c = l & 15;
  const size_t rowbase = (size_t)blockIdx.x * 128;

  // Stage ws -> LDS: 7 chunks of 8KB (512 lanes x 16B), linear both sides.
#pragma unroll
  for (int i = 0; i < 7; ++i) {
    const int off = i * 8192 + t * 16;
    if (off < WS_STAGE) {
      __builtin_amdgcn_global_load_lds(
          (const __attribute__((address_space(1))) void*)(wsb + off),
          (__attribute__((address_space(3))) void*)(wlds + off), 16, 0, 0);
    }
  }

  // this lane's batch row (B-fragment n = l&15); k-slice owned: 8g..8g+7 (+32s)
  const float* __restrict__ xrow = x + (rowbase + 16 * w + c) * IN_;

  // ---- 4-tile rolling x pipeline: preload tiles 0..3 BEFORE the barrier ----
  // (their ~500-600cy L3 latency hides under the staging vmcnt(0) drain)
  f32x4 xr[8];   // slot p holds tile (s: s&3==p): 2 f32x4 each, 32 VGPR total
#pragma unroll
  for (int p = 0; p < 4; ++p) {
    xr[2 * p]     = *(const f32x4*)(xrow + 32 * p + 8 * g);
    xr[2 * p + 1] = *(const f32x4*)(xrow + 32 * p + 8 * g + 4);
  }

  __syncthreads();   // drains vmcnt -> staged image + xr tiles 0..3 ready

  const float* pars = (const float*)(wlds + PAR);
  const float So = pars[403];

  f32x4 acc[4];
#pragma unroll
  for (int ht = 0; ht < 4; ++ht) acc[ht] = f32x4{0.f, 0.f, 0.f, 0.f};

  // ---- Layer 1: 8 k-tiles of 32, 3 exact bf16 limbs; rolling distance-4 loads ----
#pragma unroll
  for (int s = 0; s < 8; ++s) {
    // consume this tile's slot into locals FIRST...
    const f32x4 e0 = xr[2 * (s & 3)];
    const f32x4 e1 = xr[2 * (s & 3) + 1];
    // ...then refill the slot with tile s+4 (issue-to-use distance = 4 tiles)
    if (s < 4) {
      xr[2 * (s & 3)]     = *(const f32x4*)(xrow + 32 * (s + 4) + 8 * g);
      xr[2 * (s & 3) + 1] = *(const f32x4*)(xrow + 32 * (s + 4) + 8 * g + 4);
    }

    u32x4 wf[4];
#pragma unroll
    for (int ht = 0; ht < 4; ++ht)
      wf[ht] = *(const u32x4*)(wlds + W1F + (size_t)(((ht * 8 + s) * 64) + l) * 16);

    const float el[8] = {e0.x, e0.y, e0.z, e0.w, e1.x, e1.y, e1.z, e1.w};

    float d[8], e2[8];
#pragma unroll
    for (int q = 0; q < 8; ++q) d[q] = el[q] - truncbf(el[q]);   // exact
#pragma unroll
    for (int q = 0; q < 8; ++q) e2[q] = d[q] - truncbf(d[q]);    // exact

    union { uint32_t u[4]; bf16x8 v; } bh, bl1, bl2;
#pragma unroll
    for (int q = 0; q < 4; ++q) {
      bh.u[q]  = packbf(el[2 * q], el[2 * q + 1]);
      bl1.u[q] = packbf(d[2 * q],  d[2 * q + 1]);
      bl2.u[q] = packbf(e2[2 * q], e2[2 * q + 1]);
    }
#pragma unroll
    for (int ht = 0; ht < 4; ++ht) acc[ht] = MFMA(wf[ht], bh.v,  acc[ht]);
#pragma unroll
    for (int ht = 0; ht < 4; ++ht) acc[ht] = MFMA(wf[ht], bl1.v, acc[ht]);
#pragma unroll
    for (int ht = 0; ht < 4; ++ht) acc[ht] = MFMA(wf[ht], bl2.v, acc[ht]);
  }

  uint8_t* bw = &bnc[w][0];
  bf16x8 bfr[2];

  // ---- Layer 2 ----
  epilog(acc, pars, 0, bw, g, c, bfr);
  f32x4 a2[4];
#pragma unroll
  for (int ht = 0; ht < 4; ++ht) a2[ht] = f32x4{0.f, 0.f, 0.f, 0.f};
#pragma unroll
  for (int kt = 0; kt < 2; ++kt) {
#pragma unroll
    for (int ht = 0; ht < 4; ++ht) {
      const u32x4 wf = *(const u32x4*)(wlds + W2F + (size_t)(((ht * 2 + kt) * 64) + l) * 16);
      a2[ht] = MFMA(wf, bfr[kt], a2[ht]);
    }
  }

  // ---- Layer 3 ----
  epilog(a2, pars, 1, bw, g, c, bfr);
  f32x4 a3[4];
#pragma unroll
  for (int ht = 0; ht < 4; ++ht) a3[ht] = f32x4{0.f, 0.f, 0.f, 0.f};
#pragma unroll
  for (int kt = 0; kt < 2; ++kt) {
#pragma unroll
    for (int ht = 0; ht < 4; ++ht) {
      const u32x4 wf = *(const u32x4*)(wlds + W3F + (size_t)(((ht * 2 + kt) * 64) + l) * 16);
      a3[ht] = MFMA(wf, bfr[kt], a3[ht]);
    }
  }

  // ---- Output layer ----
  epilog(a3, pars, 2, bw, g, c, bfr);
  f32x4 ao = f32x4{0.f, 0.f, 0.f, 0.f};
#pragma unroll
  for (int kt = 0; kt < 2; ++kt) {
    const u32x4 wf = *(const u32x4*)(wlds + WOF + (size_t)((kt * 64) + l) * 16);
    ao = MFMA(wf, bfr[kt], ao);
  }

  const float bo0 = pars[384 + 4 * g + 0];
  const float bo1 = pars[384 + 4 * g + 1];
  const float bo2 = pars[384 + 4 * g + 2];
  const float bo3 = pars[384 + 4 * g + 3];
  f32x4 o;
  o.x = fmaf(ao.x, So, bo0);
  o.y = fmaf(ao.y, So, bo1);
  o.z = fmaf(ao.z, So, bo2);
  o.w = fmaf(ao.w, So, bo3);
  if (g < 3)  // out channels 4g..4g+3; only 0..11 exist
    *(f32x4*)(out + (rowbase + 16 * w + c) * C_ + 4 * g) = o;
}

extern "C" void kernel_launch(void* const* d_in, const int* in_sizes, int n_in,
                              void* d_out, int out_size, void* d_ws, size_t ws_size,
                              hipStream_t stream) {
  // 0:x 1:W1 2:g1 3:b1 4:s1 5:W2 6:g2 7:b2 8:s2 9:W3 10:g3 11:b3 12:s3 13:Wo 14:bo
  const float* x  = (const float*)d_in[0];
  const float* W1 = (const float*)d_in[1];
  const float* g1 = (const float*)d_in[2];
  const float* b1 = (const float*)d_in[3];
  const float* s1 = (const float*)d_in[4];
  const float* W2 = (const float*)d_in[5];
  const float* g2 = (const float*)d_in[6];
  const float* b2 = (const float*)d_in[7];
  const float* s2 = (const float*)d_in[8];
  const float* W3 = (const float*)d_in[9];
  const float* g3 = (const float*)d_in[10];
  const float* b3 = (const float*)d_in[11];
  const float* s3 = (const float*)d_in[12];
  const float* Wo = (const float*)d_in[13];
  const float* bo = (const float*)d_in[14];

  uint8_t* ws = (uint8_t*)d_ws;
  float* out = (float*)d_out;

  prep_kernel<<<4, 1024, 0, stream>>>(W1, W2, W3, Wo, g1, b1, s1, g2, b2, s2,
                                      g3, b3, s3, bo, ws);
  fused_mfma_kernel<<<B_ / 128, 512, 0, stream>>>(x, ws, out);
}